// Round 1
// baseline (251.657 us; speedup 1.0000x reference)
//
#include <hip/hip_runtime.h>

#define HIMG 192
#define HWSZ (192*192)
#define NWX  24

typedef __bf16 bf16;
typedef __bf16 bf16x2 __attribute__((ext_vector_type(2)));
typedef __bf16 bf16x4 __attribute__((ext_vector_type(4)));
typedef __bf16 bf16x8 __attribute__((ext_vector_type(8)));
typedef float  f32x4  __attribute__((ext_vector_type(4)));

#define MFMA(a,b,c) __builtin_amdgcn_mfma_f32_16x16x32_bf16((a),(b),(c),0,0,0)

__device__ __forceinline__ bf16x8 ldg8(const float* p) {
    const float4 u = ((const float4*)p)[0];
    const float4 v = ((const float4*)p)[1];
    bf16x8 r;
    r[0]=(bf16)u.x; r[1]=(bf16)u.y; r[2]=(bf16)u.z; r[3]=(bf16)u.w;
    r[4]=(bf16)v.x; r[5]=(bf16)v.y; r[6]=(bf16)v.z; r[7]=(bf16)v.w;
    return r;
}

// Precompute relative-position bias table: wb[h][i][j], 4*64*64 f32 = 64KB
__global__ __launch_bounds__(256) void bias_setup(const float* __restrict__ rpb,
                                                  float* __restrict__ wb) {
    const int e = blockIdx.x * 256 + threadIdx.x;   // 0..16383
    const int h = e >> 12, i = (e >> 6) & 63, j = e & 63;
    const int dy = (i >> 3) - (j >> 3) + 7;
    const int dx = (i & 7)  - (j & 7)  + 7;
    wb[e] = rpb[(dy * 15 + dx) * 4 + h];
}

template<int WSB>
__global__ __launch_bounds__(256, 2)
void swin_fused(const float* __restrict__ x, const float* __restrict__ qkv_w,
                const float* __restrict__ qkv_b, const float* __restrict__ proj_w,
                const float* __restrict__ proj_b, const float* __restrict__ rpb,
                const float* __restrict__ wb, float* __restrict__ out)
{
    __shared__ char smem[65536];
    char* const sX  = smem;          // [64] rows x 256B bf16 (X window; later attn-out)
    char* const sQ  = smem + 16384;  // [64] rows x 256B (Q all heads; later P heads 0,1)
    char* const sK  = smem + 32768;  // [64] rows x 256B (K all heads; later P heads 2,3)
    char* const sVT = smem + 49152;  // [128] rows x 128B (V^T: row=channel, col=token)

    const int tid  = threadIdx.x;
    const int lane = tid & 63;
    const int wvid = tid >> 6;       // wave id == head id
    const int lo   = lane & 15;
    const int hi   = lane >> 4;

    // XCD-chunked swizzle: 4608 blocks = 8 XCDs x 576 windows (one batch per XCD)
    const int bid   = blockIdx.x;
    const int batch = bid & 7;
    const int wrem  = bid >> 3;      // 0..575
    const int wy    = wrem / NWX;
    const int wx    = wrem - wy * NWX;

    const f32x4 FZ = {0.f, 0.f, 0.f, 0.f};

    // ---------------- Phase 1: gather+roll X window -> LDS bf16 (swizzled) ----
    {
        const int t  = lane;
        const int iy = t >> 3, ix = t & 7;
        int hh = wy*8 + iy + 4; if (hh >= HIMG) hh -= HIMG;
        int ww = wx*8 + ix + 4; if (ww >= HIMG) ww -= HIMG;
        const float* xp = x + (long)batch * 128 * HWSZ + hh * HIMG + ww;
        char* const wp = sX + t * 256;
        const int swz = (t & 7) << 4;
        #pragma unroll
        for (int it = 0; it < 16; ++it) {
            const int cp = wvid + it * 4;        // channel-pair 0..63
            const float v0 = xp[(2*cp)   * HWSZ];
            const float v1 = xp[(2*cp+1) * HWSZ];
            bf16x2 pk; pk[0] = (bf16)v0; pk[1] = (bf16)v1;
            *(bf16x2*)(wp + ((4*cp) ^ swz)) = pk;
        }
    }
    __syncthreads();   // B0

    const float SCALE = 0.17677669529663687f;   // 32^-0.5

    // ---------------- Phase 2a: Q^T = Wq @ X^T (head wvid) ---------------------
    {
        f32x4 acc[2][4];
        #pragma unroll
        for (int a = 0; a < 2; ++a)
            #pragma unroll
            for (int n = 0; n < 4; ++n) acc[a][n] = FZ;
        #pragma unroll
        for (int kb = 0; kb < 4; ++kb) {
            const int colb = kb*64 + hi*16;
            bf16x8 xf[4];
            #pragma unroll
            for (int n = 0; n < 4; ++n) {
                const int row = n*16 + lo;
                xf[n] = *(const bf16x8*)(sX + row*256 + (colb ^ ((row & 7) << 4)));
            }
            const int coff = kb*32 + hi*8;
            const bf16x8 w0 = ldg8(qkv_w + (wvid*32 + lo)      * 128 + coff);
            const bf16x8 w1 = ldg8(qkv_w + (wvid*32 + 16 + lo) * 128 + coff);
            #pragma unroll
            for (int n = 0; n < 4; ++n) {
                acc[0][n] = MFMA(w0, xf[n], acc[0][n]);
                acc[1][n] = MFMA(w1, xf[n], acc[1][n]);
            }
        }
        #pragma unroll
        for (int a = 0; a < 2; ++a) {
            const int dbase = wvid*32 + a*16 + hi*4;
            const float4 bq = *(const float4*)(qkv_b + dbase);
            const int colb2 = 2 * dbase;
            #pragma unroll
            for (int n = 0; n < 4; ++n) {
                const int t = n*16 + lo;
                bf16x4 q4;
                q4[0] = (bf16)((acc[a][n][0] + bq.x) * SCALE);
                q4[1] = (bf16)((acc[a][n][1] + bq.y) * SCALE);
                q4[2] = (bf16)((acc[a][n][2] + bq.z) * SCALE);
                q4[3] = (bf16)((acc[a][n][3] + bq.w) * SCALE);
                *(bf16x4*)(sQ + t*256 + (colb2 ^ ((t & 7) << 4))) = q4;
            }
        }
    }

    // ---------------- Phase 2b: K^T = Wk @ X^T --------------------------------
    {
        f32x4 acc[2][4];
        #pragma unroll
        for (int a = 0; a < 2; ++a)
            #pragma unroll
            for (int n = 0; n < 4; ++n) acc[a][n] = FZ;
        #pragma unroll
        for (int kb = 0; kb < 4; ++kb) {
            const int colb = kb*64 + hi*16;
            bf16x8 xf[4];
            #pragma unroll
            for (int n = 0; n < 4; ++n) {
                const int row = n*16 + lo;
                xf[n] = *(const bf16x8*)(sX + row*256 + (colb ^ ((row & 7) << 4)));
            }
            const int coff = kb*32 + hi*8;
            const bf16x8 w0 = ldg8(qkv_w + (128 + wvid*32 + lo)      * 128 + coff);
            const bf16x8 w1 = ldg8(qkv_w + (128 + wvid*32 + 16 + lo) * 128 + coff);
            #pragma unroll
            for (int n = 0; n < 4; ++n) {
                acc[0][n] = MFMA(w0, xf[n], acc[0][n]);
                acc[1][n] = MFMA(w1, xf[n], acc[1][n]);
            }
        }
        #pragma unroll
        for (int a = 0; a < 2; ++a) {
            const int dbase = wvid*32 + a*16 + hi*4;
            const float4 bk = *(const float4*)(qkv_b + 128 + dbase);
            const int colb2 = 2 * dbase;
            #pragma unroll
            for (int n = 0; n < 4; ++n) {
                const int t = n*16 + lo;
                bf16x4 k4;
                k4[0] = (bf16)(acc[a][n][0] + bk.x);
                k4[1] = (bf16)(acc[a][n][1] + bk.y);
                k4[2] = (bf16)(acc[a][n][2] + bk.z);
                k4[3] = (bf16)(acc[a][n][3] + bk.w);
                *(bf16x4*)(sK + t*256 + (colb2 ^ ((t & 7) << 4))) = k4;
            }
        }
    }

    // ---------------- Phase 2c: V = X @ Wv^T  (lands as V^T in LDS) -----------
    {
        f32x4 acc[4][2];
        #pragma unroll
        for (int m = 0; m < 4; ++m)
            #pragma unroll
            for (int o = 0; o < 2; ++o) acc[m][o] = FZ;
        #pragma unroll
        for (int kb = 0; kb < 4; ++kb) {
            const int colb = kb*64 + hi*16;
            bf16x8 xf[4];
            #pragma unroll
            for (int m = 0; m < 4; ++m) {
                const int row = m*16 + lo;
                xf[m] = *(const bf16x8*)(sX + row*256 + (colb ^ ((row & 7) << 4)));
            }
            const int coff = kb*32 + hi*8;
            const bf16x8 w0 = ldg8(qkv_w + (256 + wvid*32 + lo)      * 128 + coff);
            const bf16x8 w1 = ldg8(qkv_w + (256 + wvid*32 + 16 + lo) * 128 + coff);
            #pragma unroll
            for (int m = 0; m < 4; ++m) {
                acc[m][0] = MFMA(xf[m], w0, acc[m][0]);
                acc[m][1] = MFMA(xf[m], w1, acc[m][1]);
            }
        }
        #pragma unroll
        for (int o = 0; o < 2; ++o) {
            const int dcol = wvid*32 + o*16 + lo;       // channel row in V^T
            const float bv = qkv_b[256 + dcol];
            #pragma unroll
            for (int m = 0; m < 4; ++m) {
                const int t0 = m*16 + hi*4;
                bf16x4 v4;
                v4[0] = (bf16)(acc[m][o][0] + bv);
                v4[1] = (bf16)(acc[m][o][1] + bv);
                v4[2] = (bf16)(acc[m][o][2] + bv);
                v4[3] = (bf16)(acc[m][o][3] + bv);
                *(bf16x4*)(sVT + dcol*128 + ((2*t0) ^ ((dcol & 7) << 4))) = v4;
            }
        }
    }
    __syncthreads();   // B1: Q,K,V^T visible

    // ---------------- Phase 3: S^T = K @ Q^T, bias+mask, softmax --------------
    f32x4 s[4][4];
    {
        bf16x8 kf[4], qf[4];
        const int colb = wvid*64 + hi*16;   // head's 32-d slice
        #pragma unroll
        for (int m = 0; m < 4; ++m) {
            const int row = m*16 + lo;
            const int off = row*256 + (colb ^ ((row & 7) << 4));
            kf[m] = *(const bf16x8*)(sK + off);
            qf[m] = *(const bf16x8*)(sQ + off);
        }
        #pragma unroll
        for (int m = 0; m < 4; ++m)
            #pragma unroll
            for (int n = 0; n < 4; ++n)
                s[m][n] = MFMA(kf[m], qf[n], FZ);
    }
    const bool ey = (wy == 23), ex = (wx == 23);
    #pragma unroll
    for (int n = 0; n < 4; ++n) {
        const int i_ = n*16 + lo;
        const int yi = i_ >> 3, xi = i_ & 7;
        const int ri = (ey ? (yi < 4 ? 1 : 2) : 0) * 3 + (ex ? (xi < 4 ? 1 : 2) : 0);
        #pragma unroll
        for (int m = 0; m < 4; ++m) {
            const int j0 = m*16 + hi*4;
            f32x4 bb = FZ;
            if (WSB) bb = *(const f32x4*)(wb + (wvid*64 + i_)*64 + j0);
            #pragma unroll
            for (int r = 0; r < 4; ++r) {
                const int j_ = j0 + r;
                const int yj = j_ >> 3, xj = j_ & 7;
                float bias;
                if (WSB) bias = bb[r];
                else     bias = rpb[((yi - yj + 7) * 15 + (xi - xj + 7)) * 4 + wvid];
                const int rj = (ey ? (yj < 4 ? 1 : 2) : 0) * 3 + (ex ? (xj < 4 ? 1 : 2) : 0);
                s[m][n][r] += bias + ((ri != rj) ? -100.0f : 0.0f);
            }
        }
    }
    float rinv[4];
    #pragma unroll
    for (int n = 0; n < 4; ++n) {
        float mx = -1e30f;
        #pragma unroll
        for (int m = 0; m < 4; ++m)
            #pragma unroll
            for (int r = 0; r < 4; ++r) mx = fmaxf(mx, s[m][n][r]);
        mx = fmaxf(mx, __shfl_xor(mx, 16));
        mx = fmaxf(mx, __shfl_xor(mx, 32));
        float sum = 0.f;
        #pragma unroll
        for (int m = 0; m < 4; ++m)
            #pragma unroll
            for (int r = 0; r < 4; ++r) {
                const float p = __expf(s[m][n][r] - mx);
                s[m][n][r] = p; sum += p;
            }
        sum += __shfl_xor(sum, 16);
        sum += __shfl_xor(sum, 32);
        rinv[n] = 1.0f / sum;
    }
    __syncthreads();   // B2: all S^T reads of Q/K complete before P overwrites them

    char* const myP = sQ + wvid * 8192;   // P[head] aliases Q/K space, [i][j] bf16
    #pragma unroll
    for (int n = 0; n < 4; ++n) {
        const int i_ = n*16 + lo;
        #pragma unroll
        for (int m = 0; m < 4; ++m) {
            bf16x4 p4;
            p4[0]=(bf16)s[m][n][0]; p4[1]=(bf16)s[m][n][1];
            p4[2]=(bf16)s[m][n][2]; p4[3]=(bf16)s[m][n][3];
            const int colb = 2*(m*16 + hi*4);
            *(bf16x4*)(myP + i_*128 + (colb ^ ((i_ & 7) << 4))) = p4;
        }
    }
    __syncthreads();   // B3

    // ---------------- Phase 4: O^T = V^T @ P^T --------------------------------
    f32x4 o0[2][4];
    #pragma unroll
    for (int d = 0; d < 2; ++d)
        #pragma unroll
        for (int n = 0; n < 4; ++n) o0[d][n] = FZ;
    #pragma unroll
    for (int kb = 0; kb < 2; ++kb) {
        const int colb = kb*64 + hi*16;
        bf16x8 vf[2], pf[4];
        #pragma unroll
        for (int d = 0; d < 2; ++d) {
            const int row = wvid*32 + d*16 + lo;
            vf[d] = *(const bf16x8*)(sVT + row*128 + (colb ^ ((row & 7) << 4)));
        }
        #pragma unroll
        for (int n = 0; n < 4; ++n) {
            const int row = n*16 + lo;
            pf[n] = *(const bf16x8*)(myP + row*128 + (colb ^ ((row & 7) << 4)));
        }
        #pragma unroll
        for (int d = 0; d < 2; ++d)
            #pragma unroll
            for (int n = 0; n < 4; ++n)
                o0[d][n] = MFMA(vf[d], pf[n], o0[d][n]);
    }
    // attn-out (bf16, [t][c]) into sX space; divide by softmax sum here
    #pragma unroll
    for (int d = 0; d < 2; ++d) {
        const int c0 = wvid*32 + d*16 + hi*4;
        #pragma unroll
        for (int n = 0; n < 4; ++n) {
            const int t = n*16 + lo;
            bf16x4 a4;
            a4[0] = (bf16)(o0[d][n][0] * rinv[n]);
            a4[1] = (bf16)(o0[d][n][1] * rinv[n]);
            a4[2] = (bf16)(o0[d][n][2] * rinv[n]);
            a4[3] = (bf16)(o0[d][n][3] * rinv[n]);
            *(bf16x4*)(sX + t*256 + ((2*c0) ^ ((t & 7) << 4))) = a4;
        }
    }
    __syncthreads();   // B4

    // ---------------- Phase 5: out^T = Wproj @ AO^T, scatter ------------------
    {
        f32x4 pr[2][4];
        #pragma unroll
        for (int a = 0; a < 2; ++a)
            #pragma unroll
            for (int n = 0; n < 4; ++n) pr[a][n] = FZ;
        #pragma unroll
        for (int kb = 0; kb < 4; ++kb) {
            const int colb = kb*64 + hi*16;
            bf16x8 af[4];
            #pragma unroll
            for (int n = 0; n < 4; ++n) {
                const int row = n*16 + lo;
                af[n] = *(const bf16x8*)(sX + row*256 + (colb ^ ((row & 7) << 4)));
            }
            const int coff = kb*32 + hi*8;
            const bf16x8 w0 = ldg8(proj_w + (wvid*32 + lo)      * 128 + coff);
            const bf16x8 w1 = ldg8(proj_w + (wvid*32 + 16 + lo) * 128 + coff);
            #pragma unroll
            for (int n = 0; n < 4; ++n) {
                pr[0][n] = MFMA(w0, af[n], pr[0][n]);
                pr[1][n] = MFMA(w1, af[n], pr[1][n]);
            }
        }
        #pragma unroll
        for (int a = 0; a < 2; ++a) {
            const int ocb = wvid*32 + a*16 + hi*4;
            const float4 pb = *(const float4*)(proj_b + ocb);
            #pragma unroll
            for (int n = 0; n < 4; ++n) {
                const int t = n*16 + lo;
                const int iy = t >> 3, ix = t & 7;
                int hh = wy*8 + iy + 4; if (hh >= HIMG) hh -= HIMG;
                int ww = wx*8 + ix + 4; if (ww >= HIMG) ww -= HIMG;
                float* op = out + (long)(batch*128 + ocb) * HWSZ + hh*HIMG + ww;
                op[0]      = pr[a][n][0] + pb.x;
                op[HWSZ]   = pr[a][n][1] + pb.y;
                op[2*HWSZ] = pr[a][n][2] + pb.z;
                op[3*HWSZ] = pr[a][n][3] + pb.w;
            }
        }
    }
}

extern "C" void kernel_launch(void* const* d_in, const int* in_sizes, int n_in,
                              void* d_out, int out_size, void* d_ws, size_t ws_size,
                              hipStream_t stream) {
    const float* x      = (const float*)d_in[0];
    const float* qkv_w  = (const float*)d_in[1];
    const float* qkv_b  = (const float*)d_in[2];
    const float* proj_w = (const float*)d_in[3];
    const float* proj_b = (const float*)d_in[4];
    const float* rpb    = (const float*)d_in[5];
    float* out = (float*)d_out;

    if (ws_size >= 16384 * sizeof(float)) {
        float* wbias = (float*)d_ws;
        bias_setup<<<64, 256, 0, stream>>>(rpb, wbias);
        swin_fused<1><<<4608, 256, 0, stream>>>(x, qkv_w, qkv_b, proj_w, proj_b, rpb, wbias, out);
    } else {
        swin_fused<0><<<4608, 256, 0, stream>>>(x, qkv_w, qkv_b, proj_w, proj_b, rpb, nullptr, out);
    }
}